// Round 14
// baseline (194.122 us; speedup 1.0000x reference)
//
#include <hip/hip_runtime.h>
#include <hip/hip_bf16.h>

#define NN 10000
#define NE 320000
#define FDIM 128
#define NRBF 20
#define PHI_DIM 384
#define NKEY NN
#define SCAN_BLOCKS 40  // 40*256 = 10240 >= NKEY+1

typedef unsigned int uint;
typedef unsigned short ushort;

#if __has_builtin(__builtin_amdgcn_fdot2_f32_bf16)
#define USE_DOT2 1
typedef __bf16 bf16x2 __attribute__((ext_vector_type(2)));
#else
#define USE_DOT2 0
#endif

__device__ __forceinline__ ushort f2bf(float x) {
  __hip_bfloat16 b = __float2bfloat16(x);
  return *(ushort*)&b;
}
__device__ __forceinline__ float bflo(uint u) { return __uint_as_float(u << 16); }
__device__ __forceinline__ float bfhi(uint u) { return __uint_as_float(u & 0xffff0000u); }

// tab row (1280 B): [0,512) uint wy|wx ; [512,1024) uint phi1|wz ; [1024,1280) ushort phi2
//   (w* = vf*·phi0 precomputed)
// edata record (48 B = 3 x uint4):
//   dword0     : dy_bf16<<16 | dx_bf16
//   dword1..11 : rbp[11]; pairs 0..9 = (rbf*c) bf16 pairs; pair10 = dz_bf16<<16 | c_bf16
//   (node-side wr pair10 = (br_col, 0) so dot2 yields br*c; dz rides in the high half)
// offsets[] are PARTIAL (within-scan1-block); final = offsets[k] + blocksums[k>>8]
// except offsets[NN] which scan2 writes as the final total (=NE).

// ---------------- node MLP (16 nodes/block) + fused edge-count + w-plane pack ----------
__global__ void phi_kernel(const float* __restrict__ S, const float* __restrict__ W1,
                           const float* __restrict__ b1, const float* __restrict__ W2,
                           const float* __restrict__ b2, const float* __restrict__ vf,
                           const int* __restrict__ idx_i, int* __restrict__ counts,
                           char* __restrict__ tab) {
  __shared__ float s_s[16][FDIM];
  __shared__ float h_s[16][FDIM];
  const int t = threadIdx.x;
  const int n0 = blockIdx.x * 16;
  // fused: edge counting (exactly 4 edges per thread: 625*128*4 == NE)
  {
    const int e0 = (blockIdx.x * 128 + t) * 4;
#pragma unroll
    for (int q = 0; q < 4; q++) atomicAdd(&counts[idx_i[e0 + q]], 1);
  }
#pragma unroll
  for (int n = 0; n < 16; n++) s_s[n][t] = S[(n0 + n) * FDIM + t];
  __syncthreads();
  float acc[16];
#pragma unroll
  for (int n = 0; n < 16; n++) acc[n] = 0.f;
  for (int k = 0; k < FDIM; k++) {
    float w = W1[k * FDIM + t];
#pragma unroll
    for (int n = 0; n < 16; n++) acc[n] += s_s[n][k] * w;
  }
  float bb = b1[t];
#pragma unroll
  for (int n = 0; n < 16; n++) {
    float x = acc[n] + bb;
    h_s[n][t] = x / (1.0f + expf(-x));
  }
  __syncthreads();
  float a0[16], a1[16], a2[16];
#pragma unroll
  for (int n = 0; n < 16; n++) { a0[n] = 0.f; a1[n] = 0.f; a2[n] = 0.f; }
  for (int k = 0; k < FDIM; k++) {
    float w0 = W2[k * PHI_DIM + t];
    float w1 = W2[k * PHI_DIM + t + 128];
    float w2 = W2[k * PHI_DIM + t + 256];
#pragma unroll
    for (int n = 0; n < 16; n++) {
      float hv = h_s[n][k];
      a0[n] += hv * w0;
      a1[n] += hv * w1;
      a2[n] += hv * w2;
    }
  }
  float c0 = b2[t], c1 = b2[t + 128], c2 = b2[t + 256];
#pragma unroll
  for (int n = 0; n < 16; n++) {
    const int node = n0 + n;
    const float p0 = a0[n] + c0;
    const float p1 = a1[n] + c1;
    const float p2 = a2[n] + c2;
    const float* src = vf + (size_t)node * (FDIM * 3) + t * 3;
    const uint wx = f2bf(src[0] * p0);
    const uint wy = f2bf(src[1] * p0);
    const uint wz = f2bf(src[2] * p0);
    char* pb = tab + (size_t)node * 1280;
    ((uint*)pb)[t] = (wy << 16) | wx;
    ((uint*)(pb + 512))[t] = ((uint)f2bf(p1) << 16) | wz;
    ((ushort*)(pb + 1024))[t] = f2bf(p2);
  }
}

// ---------------- scan: per-block partials + block-sum scan (no add-back pass) ----------
__global__ void scan1_kernel(const int* __restrict__ counts, int* __restrict__ offsets,
                             int* __restrict__ blocksums) {
  __shared__ int s[256];
  const int t = threadIdx.x;
  const int idx = blockIdx.x * 256 + t;
  const int c = counts[idx];  // region zero-padded to 10240
  s[t] = c;
  __syncthreads();
  for (int off = 1; off < 256; off <<= 1) {
    int v = (t >= off) ? s[t - off] : 0;
    __syncthreads();
    s[t] += v;
    __syncthreads();
  }
  if (idx < NKEY) offsets[idx] = s[t] - c;  // exclusive WITHIN block (partial)
  if (t == 255) blocksums[blockIdx.x] = s[255];
}

__global__ void scan2_kernel(int* __restrict__ blocksums, int* __restrict__ offsets) {
  __shared__ int s[64];
  const int t = threadIdx.x;  // 64 threads
  int v0 = (t < SCAN_BLOCKS) ? blocksums[t] : 0;
  s[t] = v0;
  __syncthreads();
  for (int off = 1; off < 64; off <<= 1) {
    int v = (t >= off) ? s[t - off] : 0;
    __syncthreads();
    s[t] += v;
    __syncthreads();
  }
  if (t < SCAN_BLOCKS) blocksums[t] = s[t] - v0;   // exclusive base per block
  if (t == SCAN_BLOCKS - 1) offsets[NKEY] = s[t];  // FINAL total = NE
}

// ---------------- stage CSR-ordered: jlist + 48-B records ----------------
__global__ void stage_kernel(const int* __restrict__ idx_i, const int* __restrict__ idx_j,
                             const float* __restrict__ cut, const float* __restrict__ dir,
                             const float* __restrict__ rbf, const int* __restrict__ offsets,
                             const int* __restrict__ blocksums, int* __restrict__ counts,
                             uint* __restrict__ edata, int* __restrict__ jlist) {
  int e = blockIdx.x * blockDim.x + threadIdx.x;
  if (e >= NE) return;
  int i = idx_i[e];
  int pos = atomicSub(&counts[i], 1) - 1;
  const int slot = offsets[i] + blocksums[i >> 8] + pos;
  jlist[slot] = idx_j[e];
  const float c = cut[e];
  uint w[12];
  w[0] = ((uint)f2bf(dir[e * 3 + 1]) << 16) | f2bf(dir[e * 3 + 0]);
  const float* rb = rbf + (size_t)e * NRBF;
#pragma unroll
  for (int r = 0; r < 10; r++) {
    uint lo = (uint)f2bf(rb[2 * r] * c);
    uint hi = (uint)f2bf(rb[2 * r + 1] * c);
    w[1 + r] = (hi << 16) | lo;
  }
  w[11] = ((uint)f2bf(dir[e * 3 + 2]) << 16) | f2bf(c);
  uint4* d = (uint4*)(edata + (size_t)slot * 12);  // 48-B records, 16-B aligned
  d[0] = make_uint4(w[0], w[1], w[2], w[3]);
  d[1] = make_uint4(w[4], w[5], w[6], w[7]);
  d[2] = make_uint4(w[8], w[9], w[10], w[11]);
}

// ---------------- node accumulation: 1 node / 128 threads, 2-deep pipeline ----------
__global__ __launch_bounds__(128, 5) void node_kernel(
    const uint* __restrict__ edata, const int* __restrict__ jlist,
    const float* __restrict__ Wr, const float* __restrict__ br,
    const char* __restrict__ tab, const float* __restrict__ sf,
    const float* __restrict__ vf, const int* __restrict__ offsets,
    const int* __restrict__ blocksums, float* __restrict__ out) {
  const int f = threadIdx.x;  // 0..127
#if USE_DOT2
  bf16x2 wrA[11], wrB[11], wrC[11];
#pragma unroll
  for (int r = 0; r < 10; r++) {
    uint a = ((uint)f2bf(Wr[(2 * r + 1) * PHI_DIM + f]) << 16) | f2bf(Wr[(2 * r) * PHI_DIM + f]);
    uint b = ((uint)f2bf(Wr[(2 * r + 1) * PHI_DIM + f + 128]) << 16) |
             f2bf(Wr[(2 * r) * PHI_DIM + f + 128]);
    uint c = ((uint)f2bf(Wr[(2 * r + 1) * PHI_DIM + f + 256]) << 16) |
             f2bf(Wr[(2 * r) * PHI_DIM + f + 256]);
    wrA[r] = __builtin_bit_cast(bf16x2, a);
    wrB[r] = __builtin_bit_cast(bf16x2, b);
    wrC[r] = __builtin_bit_cast(bf16x2, c);
  }
  wrA[10] = __builtin_bit_cast(bf16x2, (uint)f2bf(br[f]));
  wrB[10] = __builtin_bit_cast(bf16x2, (uint)f2bf(br[f + 128]));
  wrC[10] = __builtin_bit_cast(bf16x2, (uint)f2bf(br[f + 256]));
#else
  float wrA[22], wrB[22], wrC[22];
#pragma unroll
  for (int r = 0; r < NRBF; r++) {
    wrA[r] = Wr[r * PHI_DIM + f];
    wrB[r] = Wr[r * PHI_DIM + f + 128];
    wrC[r] = Wr[r * PHI_DIM + f + 256];
  }
  wrA[20] = br[f];       wrA[21] = 0.f;
  wrB[20] = br[f + 128]; wrB[21] = 0.f;
  wrC[20] = br[f + 256]; wrC[21] = 0.f;
#endif
  const int n = blockIdx.x;
  const int beg = offsets[n] + blocksums[n >> 8];
  const int end = (n + 1 < NKEY) ? (offsets[n + 1] + blocksums[(n + 1) >> 8]) : offsets[NKEY];
  float ss = 0.f, ax = 0.f, ay = 0.f, az = 0.f;
  const int f4 = f * 4;

  auto process = [&](uint4 e0, uint4 e1, uint4 e2, uint d0, uint d1, uint zu) {
    uint rbp[11] = {e0.y, e0.z, e0.w, e1.x, e1.y, e1.z, e1.w, e2.x, e2.y, e2.z, e2.w};
    const float dx = bflo(e0.x);
    const float dy = bfhi(e0.x);
    const float dz = bfhi(rbp[10]);
    float g0 = 0.f, g1 = 0.f, g2 = 0.f;
#if USE_DOT2
#pragma unroll
    for (int r = 0; r < 11; r++) {
      bf16x2 rp = __builtin_bit_cast(bf16x2, rbp[r]);
      g0 = __builtin_amdgcn_fdot2_f32_bf16(rp, wrA[r], g0, false);
      g1 = __builtin_amdgcn_fdot2_f32_bf16(rp, wrB[r], g1, false);
      g2 = __builtin_amdgcn_fdot2_f32_bf16(rp, wrC[r], g2, false);
    }
#else
#pragma unroll
    for (int r = 0; r < 11; r++) {
      float rlo = bflo(rbp[r]);
      float rhi = bfhi(rbp[r]);
      g0 += rlo * wrA[2 * r] + rhi * wrA[2 * r + 1];
      g1 += rlo * wrB[2 * r] + rhi * wrB[2 * r + 1];
      g2 += rlo * wrC[2 * r] + rhi * wrC[2 * r + 1];
    }
#endif
    const float vs = bflo(zu) * g2;
    ss += bfhi(d1) * g1;
    ax += bflo(d0) * g0 + vs * dx;
    ay += bfhi(d0) * g0 + vs * dy;
    az += bflo(d1) * g0 + vs * dz;
  };

  int p = beg;
  for (; p + 2 <= end; p += 2) {
    const int j0 = jlist[p];
    const int j1 = jlist[p + 1];
    const char* B0 = tab + (size_t)j0 * 1280;
    const char* B1 = tab + (size_t)j1 * 1280;
    const uint d00 = *(const uint*)(B0 + f4), d01 = *(const uint*)(B0 + 512 + f4);
    const uint z0 = *(const ushort*)(B0 + 1024 + f * 2);
    const uint d10 = *(const uint*)(B1 + f4), d11 = *(const uint*)(B1 + 512 + f4);
    const uint z1 = *(const ushort*)(B1 + 1024 + f * 2);
    const uint4* r0 = (const uint4*)(edata + (size_t)p * 12);
    const uint4* r1 = (const uint4*)(edata + (size_t)(p + 1) * 12);
    uint4 a0 = r0[0], a1 = r0[1], a2 = r0[2];
    uint4 b0 = r1[0], b1 = r1[1], b2 = r1[2];
    process(a0, a1, a2, d00, d01, z0);
    process(b0, b1, b2, d10, d11, z1);
  }
  if (p < end) {
    const int j0 = jlist[p];
    const char* B0 = tab + (size_t)j0 * 1280;
    const uint d00 = *(const uint*)(B0 + f4), d01 = *(const uint*)(B0 + 512 + f4);
    const uint z0 = *(const ushort*)(B0 + 1024 + f * 2);
    const uint4* r0 = (const uint4*)(edata + (size_t)p * 12);
    process(r0[0], r0[1], r0[2], d00, d01, z0);
  }

  const float inv = 1.0f / (float)(end - beg);
  out[(size_t)n * FDIM + f] = sf[(size_t)n * FDIM + f] + ss * inv;
  float* ov = out + (size_t)NN * FDIM + (size_t)n * (FDIM * 3) + f * 3;
  const float* iv = vf + (size_t)n * (FDIM * 3) + f * 3;
  ov[0] = iv[0] + ax * inv;
  ov[1] = iv[1] + ay * inv;
  ov[2] = iv[2] + az * inv;
}

extern "C" void kernel_launch(void* const* d_in, const int* in_sizes, int n_in,
                              void* d_out, int out_size, void* d_ws, size_t ws_size,
                              hipStream_t stream) {
  const int* idx_i = (const int*)d_in[0];
  const int* idx_j = (const int*)d_in[1];
  const float* rel_dir = (const float*)d_in[2];
  const float* cut = (const float*)d_in[3];
  const float* rbf = (const float*)d_in[4];
  const float* sf = (const float*)d_in[5];
  const float* vf = (const float*)d_in[6];
  const float* W1 = (const float*)d_in[7];
  const float* b1 = (const float*)d_in[8];
  const float* W2 = (const float*)d_in[9];
  const float* b2 = (const float*)d_in[10];
  const float* Wr = (const float*)d_in[11];
  const float* br = (const float*)d_in[12];
  float* out = (float*)d_out;

  // workspace layout (bytes):
  //   counts   : [0, 40960)            10240 ints (zero-padded; consumed by stage)
  //   offsets  : [40960, 81920)        10001 ints (PARTIAL; +blocksums[k>>8])
  //   blocksums: [81920, 82176)        64 ints
  //   edata    : [90112, 15450112)     320000 * 48 B
  //   tab      : [15450112, 28250112)  10000 * 1280 B
  //   jlist    : [28250112, 29530112)  320000 ints
  char* w = (char*)d_ws;
  int* counts = (int*)w;
  int* offsets = (int*)(w + 40960);
  int* blocksums = (int*)(w + 81920);
  uint* edata = (uint*)(w + 90112);
  char* tab = w + 15450112;
  int* jlist = (int*)(w + 28250112);

  hipMemsetAsync(w, 0, 40960, stream);  // zero counts only
  hipLaunchKernelGGL(phi_kernel, dim3(NN / 16), dim3(128), 0, stream, sf, W1, b1, W2, b2, vf,
                     idx_i, counts, tab);
  hipLaunchKernelGGL(scan1_kernel, dim3(SCAN_BLOCKS), dim3(256), 0, stream, counts, offsets,
                     blocksums);
  hipLaunchKernelGGL(scan2_kernel, dim3(1), dim3(64), 0, stream, blocksums, offsets);
  hipLaunchKernelGGL(stage_kernel, dim3((NE + 255) / 256), dim3(256), 0, stream, idx_i, idx_j,
                     cut, rel_dir, rbf, offsets, blocksums, counts, edata, jlist);
  hipLaunchKernelGGL(node_kernel, dim3(NN), dim3(128), 0, stream, edata, jlist, Wr, br, tab, sf,
                     vf, offsets, blocksums, out);
}

// Round 15
// 168.204 us; speedup vs baseline: 1.1541x; 1.1541x over previous
//
#include <hip/hip_runtime.h>
#include <hip/hip_bf16.h>

#define NN 10000
#define NE 320000
#define FDIM 128
#define NRBF 20
#define PHI_DIM 384
#define NKEY NN
#define SCAN_BLOCKS 40  // 40*256 = 10240 >= NKEY+1

typedef unsigned int uint;
typedef unsigned short ushort;

#if __has_builtin(__builtin_amdgcn_fdot2_f32_bf16)
#define USE_DOT2 1
typedef __bf16 bf16x2 __attribute__((ext_vector_type(2)));
#else
#define USE_DOT2 0
#endif

__device__ __forceinline__ ushort f2bf(float x) {
  __hip_bfloat16 b = __float2bfloat16(x);
  return *(ushort*)&b;
}
__device__ __forceinline__ float bflo(uint u) { return __uint_as_float(u << 16); }
__device__ __forceinline__ float bfhi(uint u) { return __uint_as_float(u & 0xffff0000u); }

// tab row (1280 B): [0,512) uint wy|wx ; [512,1024) uint phi1|wz ; [1024,1280) ushort phi2
//   (w* = vf*·phi0 precomputed)
// edata record (48 B = 3 x uint4):
//   dword0     : dy_bf16<<16 | dx_bf16
//   dword1..11 : rbp[11]; pairs 0..9 = (rbf*c) bf16 pairs; pair10 = dz_bf16<<16 | c_bf16
//   (node-side wr pair10 = (br_col, 0) so dot2 yields br*c; dz rides in the high half)
// offsets[] are PARTIAL (within-scan1-block); final = offsets[k] + blocksums[k>>8]
// except offsets[NN] which scan2 writes as the final total (=NE).

// ---------------- node MLP (8 nodes/block, 1250 blocks) + fused count + w-pack ----------
__global__ void phi_kernel(const float* __restrict__ S, const float* __restrict__ W1,
                           const float* __restrict__ b1, const float* __restrict__ W2,
                           const float* __restrict__ b2, const float* __restrict__ vf,
                           const int* __restrict__ idx_i, int* __restrict__ counts,
                           char* __restrict__ tab) {
  __shared__ float s_s[8][FDIM];
  __shared__ float h_s[8][FDIM];
  const int t = threadIdx.x;
  const int n0 = blockIdx.x * 8;
  // fused: edge counting (exactly 2 edges per thread: 1250*128*2 == NE)
  {
    const int e0 = (blockIdx.x * 128 + t) * 2;
    atomicAdd(&counts[idx_i[e0]], 1);
    atomicAdd(&counts[idx_i[e0 + 1]], 1);
  }
#pragma unroll
  for (int n = 0; n < 8; n++) s_s[n][t] = S[(n0 + n) * FDIM + t];
  __syncthreads();
  float acc[8];
#pragma unroll
  for (int n = 0; n < 8; n++) acc[n] = 0.f;
  for (int k = 0; k < FDIM; k++) {
    float w = W1[k * FDIM + t];
#pragma unroll
    for (int n = 0; n < 8; n++) acc[n] += s_s[n][k] * w;
  }
  float bb = b1[t];
#pragma unroll
  for (int n = 0; n < 8; n++) {
    float x = acc[n] + bb;
    h_s[n][t] = x / (1.0f + expf(-x));
  }
  __syncthreads();
  float a0[8], a1[8], a2[8];
#pragma unroll
  for (int n = 0; n < 8; n++) { a0[n] = 0.f; a1[n] = 0.f; a2[n] = 0.f; }
  for (int k = 0; k < FDIM; k++) {
    float w0 = W2[k * PHI_DIM + t];
    float w1 = W2[k * PHI_DIM + t + 128];
    float w2 = W2[k * PHI_DIM + t + 256];
#pragma unroll
    for (int n = 0; n < 8; n++) {
      float hv = h_s[n][k];
      a0[n] += hv * w0;
      a1[n] += hv * w1;
      a2[n] += hv * w2;
    }
  }
  float c0 = b2[t], c1 = b2[t + 128], c2 = b2[t + 256];
#pragma unroll
  for (int n = 0; n < 8; n++) {
    const int node = n0 + n;
    const float p0 = a0[n] + c0;
    const float p1 = a1[n] + c1;
    const float p2 = a2[n] + c2;
    const float* src = vf + (size_t)node * (FDIM * 3) + t * 3;
    const uint wx = f2bf(src[0] * p0);
    const uint wy = f2bf(src[1] * p0);
    const uint wz = f2bf(src[2] * p0);
    char* pb = tab + (size_t)node * 1280;
    ((uint*)pb)[t] = (wy << 16) | wx;
    ((uint*)(pb + 512))[t] = ((uint)f2bf(p1) << 16) | wz;
    ((ushort*)(pb + 1024))[t] = f2bf(p2);
  }
}

// ---------------- scan: per-block partials + block-sum scan (no add-back pass) ----------
__global__ void scan1_kernel(const int* __restrict__ counts, int* __restrict__ offsets,
                             int* __restrict__ blocksums) {
  __shared__ int s[256];
  const int t = threadIdx.x;
  const int idx = blockIdx.x * 256 + t;
  const int c = counts[idx];  // region zero-padded to 10240
  s[t] = c;
  __syncthreads();
  for (int off = 1; off < 256; off <<= 1) {
    int v = (t >= off) ? s[t - off] : 0;
    __syncthreads();
    s[t] += v;
    __syncthreads();
  }
  if (idx < NKEY) offsets[idx] = s[t] - c;  // exclusive WITHIN block (partial)
  if (t == 255) blocksums[blockIdx.x] = s[255];
}

__global__ void scan2_kernel(int* __restrict__ blocksums, int* __restrict__ offsets) {
  __shared__ int s[64];
  const int t = threadIdx.x;  // 64 threads
  int v0 = (t < SCAN_BLOCKS) ? blocksums[t] : 0;
  s[t] = v0;
  __syncthreads();
  for (int off = 1; off < 64; off <<= 1) {
    int v = (t >= off) ? s[t - off] : 0;
    __syncthreads();
    s[t] += v;
    __syncthreads();
  }
  if (t < SCAN_BLOCKS) blocksums[t] = s[t] - v0;   // exclusive base per block
  if (t == SCAN_BLOCKS - 1) offsets[NKEY] = s[t];  // FINAL total = NE
}

// ---------------- stage CSR-ordered: jlist + 48-B records ----------------
__global__ void stage_kernel(const int* __restrict__ idx_i, const int* __restrict__ idx_j,
                             const float* __restrict__ cut, const float* __restrict__ dir,
                             const float* __restrict__ rbf, const int* __restrict__ offsets,
                             const int* __restrict__ blocksums, int* __restrict__ counts,
                             uint* __restrict__ edata, int* __restrict__ jlist) {
  int e = blockIdx.x * blockDim.x + threadIdx.x;
  if (e >= NE) return;
  int i = idx_i[e];
  int pos = atomicSub(&counts[i], 1) - 1;
  const int slot = offsets[i] + blocksums[i >> 8] + pos;
  jlist[slot] = idx_j[e];
  const float c = cut[e];
  uint w[12];
  w[0] = ((uint)f2bf(dir[e * 3 + 1]) << 16) | f2bf(dir[e * 3 + 0]);
  const float* rb = rbf + (size_t)e * NRBF;
#pragma unroll
  for (int r = 0; r < 10; r++) {
    uint lo = (uint)f2bf(rb[2 * r] * c);
    uint hi = (uint)f2bf(rb[2 * r + 1] * c);
    w[1 + r] = (hi << 16) | lo;
  }
  w[11] = ((uint)f2bf(dir[e * 3 + 2]) << 16) | f2bf(c);
  uint4* d = (uint4*)(edata + (size_t)slot * 12);  // 48-B records, 16-B aligned
  d[0] = make_uint4(w[0], w[1], w[2], w[3]);
  d[1] = make_uint4(w[4], w[5], w[6], w[7]);
  d[2] = make_uint4(w[8], w[9], w[10], w[11]);
}

// ---------------- node accumulation: 1 node / 128 threads, 2-deep pipeline ----------
__global__ __launch_bounds__(128, 5) void node_kernel(
    const uint* __restrict__ edata, const int* __restrict__ jlist,
    const float* __restrict__ Wr, const float* __restrict__ br,
    const char* __restrict__ tab, const float* __restrict__ sf,
    const float* __restrict__ vf, const int* __restrict__ offsets,
    const int* __restrict__ blocksums, float* __restrict__ out) {
  const int f = threadIdx.x;  // 0..127
#if USE_DOT2
  bf16x2 wrA[11], wrB[11], wrC[11];
#pragma unroll
  for (int r = 0; r < 10; r++) {
    uint a = ((uint)f2bf(Wr[(2 * r + 1) * PHI_DIM + f]) << 16) | f2bf(Wr[(2 * r) * PHI_DIM + f]);
    uint b = ((uint)f2bf(Wr[(2 * r + 1) * PHI_DIM + f + 128]) << 16) |
             f2bf(Wr[(2 * r) * PHI_DIM + f + 128]);
    uint c = ((uint)f2bf(Wr[(2 * r + 1) * PHI_DIM + f + 256]) << 16) |
             f2bf(Wr[(2 * r) * PHI_DIM + f + 256]);
    wrA[r] = __builtin_bit_cast(bf16x2, a);
    wrB[r] = __builtin_bit_cast(bf16x2, b);
    wrC[r] = __builtin_bit_cast(bf16x2, c);
  }
  wrA[10] = __builtin_bit_cast(bf16x2, (uint)f2bf(br[f]));
  wrB[10] = __builtin_bit_cast(bf16x2, (uint)f2bf(br[f + 128]));
  wrC[10] = __builtin_bit_cast(bf16x2, (uint)f2bf(br[f + 256]));
#else
  float wrA[22], wrB[22], wrC[22];
#pragma unroll
  for (int r = 0; r < NRBF; r++) {
    wrA[r] = Wr[r * PHI_DIM + f];
    wrB[r] = Wr[r * PHI_DIM + f + 128];
    wrC[r] = Wr[r * PHI_DIM + f + 256];
  }
  wrA[20] = br[f];       wrA[21] = 0.f;
  wrB[20] = br[f + 128]; wrB[21] = 0.f;
  wrC[20] = br[f + 256]; wrC[21] = 0.f;
#endif
  const int n = blockIdx.x;
  const int beg = offsets[n] + blocksums[n >> 8];
  const int end = (n + 1 < NKEY) ? (offsets[n + 1] + blocksums[(n + 1) >> 8]) : offsets[NKEY];
  float ss = 0.f, ax = 0.f, ay = 0.f, az = 0.f;
  const int f4 = f * 4;

  auto process = [&](uint4 e0, uint4 e1, uint4 e2, uint d0, uint d1, uint zu) {
    uint rbp[11] = {e0.y, e0.z, e0.w, e1.x, e1.y, e1.z, e1.w, e2.x, e2.y, e2.z, e2.w};
    const float dx = bflo(e0.x);
    const float dy = bfhi(e0.x);
    const float dz = bfhi(rbp[10]);
    float g0 = 0.f, g1 = 0.f, g2 = 0.f;
#if USE_DOT2
#pragma unroll
    for (int r = 0; r < 11; r++) {
      bf16x2 rp = __builtin_bit_cast(bf16x2, rbp[r]);
      g0 = __builtin_amdgcn_fdot2_f32_bf16(rp, wrA[r], g0, false);
      g1 = __builtin_amdgcn_fdot2_f32_bf16(rp, wrB[r], g1, false);
      g2 = __builtin_amdgcn_fdot2_f32_bf16(rp, wrC[r], g2, false);
    }
#else
#pragma unroll
    for (int r = 0; r < 11; r++) {
      float rlo = bflo(rbp[r]);
      float rhi = bfhi(rbp[r]);
      g0 += rlo * wrA[2 * r] + rhi * wrA[2 * r + 1];
      g1 += rlo * wrB[2 * r] + rhi * wrB[2 * r + 1];
      g2 += rlo * wrC[2 * r] + rhi * wrC[2 * r + 1];
    }
#endif
    const float vs = bflo(zu) * g2;
    ss += bfhi(d1) * g1;
    ax += bflo(d0) * g0 + vs * dx;
    ay += bfhi(d0) * g0 + vs * dy;
    az += bflo(d1) * g0 + vs * dz;
  };

  int p = beg;
  for (; p + 2 <= end; p += 2) {
    const int j0 = jlist[p];
    const int j1 = jlist[p + 1];
    const char* B0 = tab + (size_t)j0 * 1280;
    const char* B1 = tab + (size_t)j1 * 1280;
    const uint d00 = *(const uint*)(B0 + f4), d01 = *(const uint*)(B0 + 512 + f4);
    const uint z0 = *(const ushort*)(B0 + 1024 + f * 2);
    const uint d10 = *(const uint*)(B1 + f4), d11 = *(const uint*)(B1 + 512 + f4);
    const uint z1 = *(const ushort*)(B1 + 1024 + f * 2);
    const uint4* r0 = (const uint4*)(edata + (size_t)p * 12);
    const uint4* r1 = (const uint4*)(edata + (size_t)(p + 1) * 12);
    uint4 a0 = r0[0], a1 = r0[1], a2 = r0[2];
    uint4 b0 = r1[0], b1 = r1[1], b2 = r1[2];
    process(a0, a1, a2, d00, d01, z0);
    process(b0, b1, b2, d10, d11, z1);
  }
  if (p < end) {
    const int j0 = jlist[p];
    const char* B0 = tab + (size_t)j0 * 1280;
    const uint d00 = *(const uint*)(B0 + f4), d01 = *(const uint*)(B0 + 512 + f4);
    const uint z0 = *(const ushort*)(B0 + 1024 + f * 2);
    const uint4* r0 = (const uint4*)(edata + (size_t)p * 12);
    process(r0[0], r0[1], r0[2], d00, d01, z0);
  }

  const float inv = 1.0f / (float)(end - beg);
  out[(size_t)n * FDIM + f] = sf[(size_t)n * FDIM + f] + ss * inv;
  float* ov = out + (size_t)NN * FDIM + (size_t)n * (FDIM * 3) + f * 3;
  const float* iv = vf + (size_t)n * (FDIM * 3) + f * 3;
  ov[0] = iv[0] + ax * inv;
  ov[1] = iv[1] + ay * inv;
  ov[2] = iv[2] + az * inv;
}

extern "C" void kernel_launch(void* const* d_in, const int* in_sizes, int n_in,
                              void* d_out, int out_size, void* d_ws, size_t ws_size,
                              hipStream_t stream) {
  const int* idx_i = (const int*)d_in[0];
  const int* idx_j = (const int*)d_in[1];
  const float* rel_dir = (const float*)d_in[2];
  const float* cut = (const float*)d_in[3];
  const float* rbf = (const float*)d_in[4];
  const float* sf = (const float*)d_in[5];
  const float* vf = (const float*)d_in[6];
  const float* W1 = (const float*)d_in[7];
  const float* b1 = (const float*)d_in[8];
  const float* W2 = (const float*)d_in[9];
  const float* b2 = (const float*)d_in[10];
  const float* Wr = (const float*)d_in[11];
  const float* br = (const float*)d_in[12];
  float* out = (float*)d_out;

  // workspace layout (bytes):
  //   counts   : [0, 40960)            10240 ints (zero-padded; consumed by stage)
  //   offsets  : [40960, 81920)        10001 ints (PARTIAL; +blocksums[k>>8])
  //   blocksums: [81920, 82176)        64 ints
  //   edata    : [90112, 15450112)     320000 * 48 B
  //   tab      : [15450112, 28250112)  10000 * 1280 B
  //   jlist    : [28250112, 29530112)  320000 ints
  char* w = (char*)d_ws;
  int* counts = (int*)w;
  int* offsets = (int*)(w + 40960);
  int* blocksums = (int*)(w + 81920);
  uint* edata = (uint*)(w + 90112);
  char* tab = w + 15450112;
  int* jlist = (int*)(w + 28250112);

  hipMemsetAsync(w, 0, 40960, stream);  // zero counts only
  hipLaunchKernelGGL(phi_kernel, dim3(NN / 8), dim3(128), 0, stream, sf, W1, b1, W2, b2, vf,
                     idx_i, counts, tab);
  hipLaunchKernelGGL(scan1_kernel, dim3(SCAN_BLOCKS), dim3(256), 0, stream, counts, offsets,
                     blocksums);
  hipLaunchKernelGGL(scan2_kernel, dim3(1), dim3(64), 0, stream, blocksums, offsets);
  hipLaunchKernelGGL(stage_kernel, dim3((NE + 255) / 256), dim3(256), 0, stream, idx_i, idx_j,
                     cut, rel_dir, rbf, offsets, blocksums, counts, edata, jlist);
  hipLaunchKernelGGL(node_kernel, dim3(NN), dim3(128), 0, stream, edata, jlist, Wr, br, tab, sf,
                     vf, offsets, blocksums, out);
}

// Round 16
// 162.839 us; speedup vs baseline: 1.1921x; 1.0329x over previous
//
#include <hip/hip_runtime.h>
#include <hip/hip_bf16.h>

#define NN 10000
#define NE 320000
#define FDIM 128
#define NRBF 20
#define PHI_DIM 384
#define NKEY NN
#define SCAN_BLOCKS 40  // 40*256 = 10240 >= NKEY+1

typedef unsigned int uint;
typedef unsigned short ushort;

#if __has_builtin(__builtin_amdgcn_fdot2_f32_bf16)
#define USE_DOT2 1
typedef __bf16 bf16x2 __attribute__((ext_vector_type(2)));
#else
#define USE_DOT2 0
#endif

__device__ __forceinline__ ushort f2bf(float x) {
  __hip_bfloat16 b = __float2bfloat16(x);
  return *(ushort*)&b;
}
__device__ __forceinline__ float bflo(uint u) { return __uint_as_float(u << 16); }
__device__ __forceinline__ float bfhi(uint u) { return __uint_as_float(u & 0xffff0000u); }

// tab row (1280 B): [0,512) uint wy|wx ; [512,1024) uint phi1|wz ; [1024,1280) ushort phi2
//   (w* = vf*·phi0 precomputed)
// edata record (48 B = 3 x uint4):
//   dword0     : dy_bf16<<16 | dx_bf16
//   dword1..11 : rbp[11]; pairs 0..9 = (rbf*c) bf16 pairs; pair10 = dz_bf16<<16 | c_bf16
//   (node-side wr pair10 = (br_col, 0) so dot2 yields br*c; dz rides in the high half)
// offsets[] are PARTIAL (within-scan1-block); final = offsets[k] + blocksums[k>>8]
// except offsets[NN] which scan2 writes as the final total (=NE).

// ------- node MLP: 256 thr/block, two 128-thread halves x 4 nodes (1250 blocks) -------
__global__ __launch_bounds__(256) void phi_kernel(
    const float* __restrict__ S, const float* __restrict__ W1, const float* __restrict__ b1,
    const float* __restrict__ W2, const float* __restrict__ b2, const float* __restrict__ vf,
    const int* __restrict__ idx_i, int* __restrict__ counts, char* __restrict__ tab) {
  __shared__ float s_s[8][FDIM];
  __shared__ float h_s[8][FDIM];
  const int t = threadIdx.x;
  const int tf = t & 127;
  const int half = t >> 7;                       // 0..1
  const int nb = blockIdx.x * 8 + half * 4;      // this half's first node
  const int row0 = half * 4;                     // LDS row base
  // fused: edge counting (exactly 1 edge per thread: 1250*256 == NE)
  atomicAdd(&counts[idx_i[blockIdx.x * 256 + t]], 1);
#pragma unroll
  for (int n = 0; n < 4; n++) s_s[row0 + n][tf] = S[(nb + n) * FDIM + tf];
  __syncthreads();
  float acc[4];
#pragma unroll
  for (int n = 0; n < 4; n++) acc[n] = 0.f;
  for (int k = 0; k < FDIM; k++) {
    float w = W1[k * FDIM + tf];
#pragma unroll
    for (int n = 0; n < 4; n++) acc[n] += s_s[row0 + n][k] * w;
  }
  float bb = b1[tf];
#pragma unroll
  for (int n = 0; n < 4; n++) {
    float x = acc[n] + bb;
    h_s[row0 + n][tf] = x / (1.0f + expf(-x));
  }
  __syncthreads();
  float a0[4], a1[4], a2[4];
#pragma unroll
  for (int n = 0; n < 4; n++) { a0[n] = 0.f; a1[n] = 0.f; a2[n] = 0.f; }
  for (int k = 0; k < FDIM; k++) {
    float w0 = W2[k * PHI_DIM + tf];
    float w1 = W2[k * PHI_DIM + tf + 128];
    float w2 = W2[k * PHI_DIM + tf + 256];
#pragma unroll
    for (int n = 0; n < 4; n++) {
      float hv = h_s[row0 + n][k];
      a0[n] += hv * w0;
      a1[n] += hv * w1;
      a2[n] += hv * w2;
    }
  }
  float c0 = b2[tf], c1 = b2[tf + 128], c2 = b2[tf + 256];
#pragma unroll
  for (int n = 0; n < 4; n++) {
    const int node = nb + n;
    const float p0 = a0[n] + c0;
    const float p1 = a1[n] + c1;
    const float p2 = a2[n] + c2;
    const float* src = vf + (size_t)node * (FDIM * 3) + tf * 3;
    const uint wx = f2bf(src[0] * p0);
    const uint wy = f2bf(src[1] * p0);
    const uint wz = f2bf(src[2] * p0);
    char* pb = tab + (size_t)node * 1280;
    ((uint*)pb)[tf] = (wy << 16) | wx;
    ((uint*)(pb + 512))[tf] = ((uint)f2bf(p1) << 16) | wz;
    ((ushort*)(pb + 1024))[tf] = f2bf(p2);
  }
}

// ---------------- scan: per-block partials + block-sum scan (no add-back pass) ----------
__global__ void scan1_kernel(const int* __restrict__ counts, int* __restrict__ offsets,
                             int* __restrict__ blocksums) {
  __shared__ int s[256];
  const int t = threadIdx.x;
  const int idx = blockIdx.x * 256 + t;
  const int c = counts[idx];  // region zero-padded to 10240
  s[t] = c;
  __syncthreads();
  for (int off = 1; off < 256; off <<= 1) {
    int v = (t >= off) ? s[t - off] : 0;
    __syncthreads();
    s[t] += v;
    __syncthreads();
  }
  if (idx < NKEY) offsets[idx] = s[t] - c;  // exclusive WITHIN block (partial)
  if (t == 255) blocksums[blockIdx.x] = s[255];
}

__global__ void scan2_kernel(int* __restrict__ blocksums, int* __restrict__ offsets) {
  __shared__ int s[64];
  const int t = threadIdx.x;  // 64 threads
  int v0 = (t < SCAN_BLOCKS) ? blocksums[t] : 0;
  s[t] = v0;
  __syncthreads();
  for (int off = 1; off < 64; off <<= 1) {
    int v = (t >= off) ? s[t - off] : 0;
    __syncthreads();
    s[t] += v;
    __syncthreads();
  }
  if (t < SCAN_BLOCKS) blocksums[t] = s[t] - v0;   // exclusive base per block
  if (t == SCAN_BLOCKS - 1) offsets[NKEY] = s[t];  // FINAL total = NE
}

// ---------------- stage CSR-ordered: jlist + 48-B records ----------------
__global__ void stage_kernel(const int* __restrict__ idx_i, const int* __restrict__ idx_j,
                             const float* __restrict__ cut, const float* __restrict__ dir,
                             const float* __restrict__ rbf, const int* __restrict__ offsets,
                             const int* __restrict__ blocksums, int* __restrict__ counts,
                             uint* __restrict__ edata, int* __restrict__ jlist) {
  int e = blockIdx.x * blockDim.x + threadIdx.x;
  if (e >= NE) return;
  int i = idx_i[e];
  int pos = atomicSub(&counts[i], 1) - 1;
  const int slot = offsets[i] + blocksums[i >> 8] + pos;
  jlist[slot] = idx_j[e];
  const float c = cut[e];
  uint w[12];
  w[0] = ((uint)f2bf(dir[e * 3 + 1]) << 16) | f2bf(dir[e * 3 + 0]);
  const float* rb = rbf + (size_t)e * NRBF;
#pragma unroll
  for (int r = 0; r < 10; r++) {
    uint lo = (uint)f2bf(rb[2 * r] * c);
    uint hi = (uint)f2bf(rb[2 * r + 1] * c);
    w[1 + r] = (hi << 16) | lo;
  }
  w[11] = ((uint)f2bf(dir[e * 3 + 2]) << 16) | f2bf(c);
  uint4* d = (uint4*)(edata + (size_t)slot * 12);  // 48-B records, 16-B aligned
  d[0] = make_uint4(w[0], w[1], w[2], w[3]);
  d[1] = make_uint4(w[4], w[5], w[6], w[7]);
  d[2] = make_uint4(w[8], w[9], w[10], w[11]);
}

// ---- node accumulation: 1 node / 128 threads, 2-deep pipeline, scalar edge records ----
__global__ __launch_bounds__(128, 5) void node_kernel(
    const uint* __restrict__ edata, const int* __restrict__ jlist,
    const float* __restrict__ Wr, const float* __restrict__ br,
    const char* __restrict__ tab, const float* __restrict__ sf,
    const float* __restrict__ vf, const int* __restrict__ offsets,
    const int* __restrict__ blocksums, float* __restrict__ out) {
  const int f = threadIdx.x;  // 0..127
#if USE_DOT2
  bf16x2 wrA[11], wrB[11], wrC[11];
#pragma unroll
  for (int r = 0; r < 10; r++) {
    uint a = ((uint)f2bf(Wr[(2 * r + 1) * PHI_DIM + f]) << 16) | f2bf(Wr[(2 * r) * PHI_DIM + f]);
    uint b = ((uint)f2bf(Wr[(2 * r + 1) * PHI_DIM + f + 128]) << 16) |
             f2bf(Wr[(2 * r) * PHI_DIM + f + 128]);
    uint c = ((uint)f2bf(Wr[(2 * r + 1) * PHI_DIM + f + 256]) << 16) |
             f2bf(Wr[(2 * r) * PHI_DIM + f + 256]);
    wrA[r] = __builtin_bit_cast(bf16x2, a);
    wrB[r] = __builtin_bit_cast(bf16x2, b);
    wrC[r] = __builtin_bit_cast(bf16x2, c);
  }
  wrA[10] = __builtin_bit_cast(bf16x2, (uint)f2bf(br[f]));
  wrB[10] = __builtin_bit_cast(bf16x2, (uint)f2bf(br[f + 128]));
  wrC[10] = __builtin_bit_cast(bf16x2, (uint)f2bf(br[f + 256]));
#else
  float wrA[22], wrB[22], wrC[22];
#pragma unroll
  for (int r = 0; r < NRBF; r++) {
    wrA[r] = Wr[r * PHI_DIM + f];
    wrB[r] = Wr[r * PHI_DIM + f + 128];
    wrC[r] = Wr[r * PHI_DIM + f + 256];
  }
  wrA[20] = br[f];       wrA[21] = 0.f;
  wrB[20] = br[f + 128]; wrB[21] = 0.f;
  wrC[20] = br[f + 256]; wrC[21] = 0.f;
#endif
  const int n = blockIdx.x;
  // readfirstlane: prove wave-uniformity so jlist/edata loads become s_load
  const int beg = __builtin_amdgcn_readfirstlane(offsets[n] + blocksums[n >> 8]);
  const int end = __builtin_amdgcn_readfirstlane(
      (n + 1 < NKEY) ? (offsets[n + 1] + blocksums[(n + 1) >> 8]) : offsets[NKEY]);
  float ss = 0.f, ax = 0.f, ay = 0.f, az = 0.f;
  const int f4 = f * 4;

  auto process = [&](uint4 e0, uint4 e1, uint4 e2, uint d0, uint d1, uint zu) {
    uint rbp[11] = {e0.y, e0.z, e0.w, e1.x, e1.y, e1.z, e1.w, e2.x, e2.y, e2.z, e2.w};
    const float dx = bflo(e0.x);
    const float dy = bfhi(e0.x);
    const float dz = bfhi(rbp[10]);
    float g0 = 0.f, g1 = 0.f, g2 = 0.f;
#if USE_DOT2
#pragma unroll
    for (int r = 0; r < 11; r++) {
      bf16x2 rp = __builtin_bit_cast(bf16x2, rbp[r]);
      g0 = __builtin_amdgcn_fdot2_f32_bf16(rp, wrA[r], g0, false);
      g1 = __builtin_amdgcn_fdot2_f32_bf16(rp, wrB[r], g1, false);
      g2 = __builtin_amdgcn_fdot2_f32_bf16(rp, wrC[r], g2, false);
    }
#else
#pragma unroll
    for (int r = 0; r < 11; r++) {
      float rlo = bflo(rbp[r]);
      float rhi = bfhi(rbp[r]);
      g0 += rlo * wrA[2 * r] + rhi * wrA[2 * r + 1];
      g1 += rlo * wrB[2 * r] + rhi * wrB[2 * r + 1];
      g2 += rlo * wrC[2 * r] + rhi * wrC[2 * r + 1];
    }
#endif
    const float vs = bflo(zu) * g2;
    ss += bfhi(d1) * g1;
    ax += bflo(d0) * g0 + vs * dx;
    ay += bfhi(d0) * g0 + vs * dy;
    az += bflo(d1) * g0 + vs * dz;
  };

  int p = beg;
  for (; p + 2 <= end; p += 2) {
    const int j0 = __builtin_amdgcn_readfirstlane(jlist[p]);
    const int j1 = __builtin_amdgcn_readfirstlane(jlist[p + 1]);
    const char* B0 = tab + (size_t)j0 * 1280;
    const char* B1 = tab + (size_t)j1 * 1280;
    const uint d00 = *(const uint*)(B0 + f4), d01 = *(const uint*)(B0 + 512 + f4);
    const uint z0 = *(const ushort*)(B0 + 1024 + f * 2);
    const uint d10 = *(const uint*)(B1 + f4), d11 = *(const uint*)(B1 + 512 + f4);
    const uint z1 = *(const ushort*)(B1 + 1024 + f * 2);
    const uint4* r0 = (const uint4*)(edata + (size_t)p * 12);
    const uint4* r1 = (const uint4*)(edata + (size_t)(p + 1) * 12);
    uint4 a0 = r0[0], a1 = r0[1], a2 = r0[2];
    uint4 b0 = r1[0], b1 = r1[1], b2 = r1[2];
    process(a0, a1, a2, d00, d01, z0);
    process(b0, b1, b2, d10, d11, z1);
  }
  if (p < end) {
    const int j0 = __builtin_amdgcn_readfirstlane(jlist[p]);
    const char* B0 = tab + (size_t)j0 * 1280;
    const uint d00 = *(const uint*)(B0 + f4), d01 = *(const uint*)(B0 + 512 + f4);
    const uint z0 = *(const ushort*)(B0 + 1024 + f * 2);
    const uint4* r0 = (const uint4*)(edata + (size_t)p * 12);
    process(r0[0], r0[1], r0[2], d00, d01, z0);
  }

  const float inv = 1.0f / (float)(end - beg);
  out[(size_t)n * FDIM + f] = sf[(size_t)n * FDIM + f] + ss * inv;
  float* ov = out + (size_t)NN * FDIM + (size_t)n * (FDIM * 3) + f * 3;
  const float* iv = vf + (size_t)n * (FDIM * 3) + f * 3;
  ov[0] = iv[0] + ax * inv;
  ov[1] = iv[1] + ay * inv;
  ov[2] = iv[2] + az * inv;
}

extern "C" void kernel_launch(void* const* d_in, const int* in_sizes, int n_in,
                              void* d_out, int out_size, void* d_ws, size_t ws_size,
                              hipStream_t stream) {
  const int* idx_i = (const int*)d_in[0];
  const int* idx_j = (const int*)d_in[1];
  const float* rel_dir = (const float*)d_in[2];
  const float* cut = (const float*)d_in[3];
  const float* rbf = (const float*)d_in[4];
  const float* sf = (const float*)d_in[5];
  const float* vf = (const float*)d_in[6];
  const float* W1 = (const float*)d_in[7];
  const float* b1 = (const float*)d_in[8];
  const float* W2 = (const float*)d_in[9];
  const float* b2 = (const float*)d_in[10];
  const float* Wr = (const float*)d_in[11];
  const float* br = (const float*)d_in[12];
  float* out = (float*)d_out;

  // workspace layout (bytes):
  //   counts   : [0, 40960)            10240 ints (zero-padded; consumed by stage)
  //   offsets  : [40960, 81920)        10001 ints (PARTIAL; +blocksums[k>>8])
  //   blocksums: [81920, 82176)        64 ints
  //   edata    : [90112, 15450112)     320000 * 48 B
  //   tab      : [15450112, 28250112)  10000 * 1280 B
  //   jlist    : [28250112, 29530112)  320000 ints
  char* w = (char*)d_ws;
  int* counts = (int*)w;
  int* offsets = (int*)(w + 40960);
  int* blocksums = (int*)(w + 81920);
  uint* edata = (uint*)(w + 90112);
  char* tab = w + 15450112;
  int* jlist = (int*)(w + 28250112);

  hipMemsetAsync(w, 0, 40960, stream);  // zero counts only
  hipLaunchKernelGGL(phi_kernel, dim3(NN / 8), dim3(256), 0, stream, sf, W1, b1, W2, b2, vf,
                     idx_i, counts, tab);
  hipLaunchKernelGGL(scan1_kernel, dim3(SCAN_BLOCKS), dim3(256), 0, stream, counts, offsets,
                     blocksums);
  hipLaunchKernelGGL(scan2_kernel, dim3(1), dim3(64), 0, stream, blocksums, offsets);
  hipLaunchKernelGGL(stage_kernel, dim3((NE + 255) / 256), dim3(256), 0, stream, idx_i, idx_j,
                     cut, rel_dir, rbf, offsets, blocksums, counts, edata, jlist);
  hipLaunchKernelGGL(node_kernel, dim3(NN), dim3(128), 0, stream, edata, jlist, Wr, br, tab, sf,
                     vf, offsets, blocksums, out);
}